// Round 13
// baseline (4691.290 us; speedup 1.0000x reference)
//
#include <hip/hip_runtime.h>

// TrajectoryDecoder: 2-layer LSTM (H=256), 45 steps, B=4096.
// R12: R10's staged chunk pipeline (unchanged, 3.57ms, passed) + a
// PERFORMANCE-ONLY global step barrier: monotonic-generation atomic
// barrier in d_ws with bounded spin. Aligns the 32 WGs/XCD so the
// 1.57MB weight sweep stays L2-resident (R8 showed FETCH 88MB when
// aligned; R10 free-running = 4GB refetch at the ~1.13TB/s L3->L2
// fill wall). Bounded spin => no deadlock risk; barrier affects
// timing only, never results. Barrier words zeroed via
// hipMemsetAsync each launch (poison-safe, graph-safe).
// BB=16, 256 WGs x 512 thr. Weights bf16 chunk-major in d_ws.
// mfma_f32_16x16x32_bf16: A row=lane&15(batch), k=(lane>>4)*8+j;
//   B col=lane&15(gate unit); C/D row=(lane>>4)*4+q, col=lane&15.

#define BB    16
#define TPB   512
#define HN    256
#define DM    128
#define NSTEP 45
#define NWG   256
#define BAR_OFF 1605632   // bytes; right after 802816 ushorts of weights

typedef __attribute__((ext_vector_type(8))) short s8v;
typedef __attribute__((ext_vector_type(4))) float f32x4;

#define MFMA16(a,b,c) __builtin_amdgcn_mfma_f32_16x16x32_bf16((a),(b),(c),0,0,0)

__device__ __forceinline__ unsigned short f2bf(float f){
  union { float f; unsigned u; } x; x.f = f;
  unsigned r = x.u + 0x7fffu + ((x.u >> 16) & 1u);
  return (unsigned short)(r >> 16);
}
__device__ __forceinline__ float bf2f(unsigned short h){
  union { unsigned u; float f; } x; x.u = ((unsigned)h) << 16;
  return x.f;
}
__device__ __forceinline__ float sigm(float x){
  x = fminf(40.f, fmaxf(-40.f, x));
  return 1.f/(1.f + __expf(-x));
}
__device__ __forceinline__ float tanhx(float x){
  float xx = fminf(15.f, fmaxf(-15.f, x));
  float e = __expf(2.f*xx);
  return (e-1.f)/(e+1.f);
}

// h LDS: bf16 [16 rows][256], row b element u stored at u ^ ((b&7)<<3)
__device__ __forceinline__ void write_h(unsigned short* lds, int b, int u, float v){
  lds[b*HN + (u ^ ((b&7)<<3))] = f2bf(v);
}
__device__ __forceinline__ s8v read_afrag(const unsigned short* lds, int b, int hi, int kt){
  int blk = (kt*4 + hi) ^ (b & 7);
  return *(const s8v*)(lds + b*HN + blk*8);
}

// ---- repack (R10 layout): fp32 row-major -> bf16 tiles, CHUNK-MAJOR ----
// d_ws (ushort): Whh0[262144] | Wih1[262144] | Whh1[262144] | Wp1[16384]
// big matrices: tile r=(g*8+kt)*16+ut at mi*262144 + r*512 + lane*8 holds
//   W[g*256+ut*16+(lane&15)][kt*32+(lane>>4)*8+j]
// chunk (g,kh)=32KB at (g*4+kh)*16384 contiguous (kt=2kh,2kh+1; all ut).
// Wp1: tile r2=pt*8+kt at 786432+r2*512+lane*8, row pt*16+(lane&15).
__global__ void repack(const float* __restrict__ Whh0, const float* __restrict__ Wih1,
                       const float* __restrict__ Whh1, const float* __restrict__ Wp1,
                       unsigned short* __restrict__ dst){
  int gid  = blockIdx.x*256 + threadIdx.x;
  int lane = gid & 63;
  int tile = gid >> 6;
  const float* src; int row; size_t doff;
  int k0 = (lane>>4)*8;
  if (tile < 1536){
    int mi = tile / 512;
    int r  = tile % 512;          // (g*8+kt)*16+ut
    int ut = r & 15;
    int kt = (r >> 4) & 7;
    int g  = r >> 7;
    src  = (mi==0) ? Whh0 : (mi==1) ? Wih1 : Whh1;
    row  = g*256 + ut*16 + (lane&15);
    k0  += kt*32;
    doff = (size_t)mi*262144 + (size_t)r*512 + lane*8;
  } else {
    int r2 = tile - 1536;         // pt*8+kt
    int kt = r2 & 7, pt = r2 >> 3;
    src  = Wp1;
    row  = pt*16 + (lane&15);
    k0  += kt*32;
    doff = 786432 + (size_t)r2*512 + lane*8;
  }
  const float* s = src + (size_t)row*HN + k0;
  float4 a = *(const float4*)(s);
  float4 b = *(const float4*)(s+4);
  unsigned short* d = dst + doff;
  d[0]=f2bf(a.x); d[1]=f2bf(a.y); d[2]=f2bf(a.z); d[3]=f2bf(a.w);
  d[4]=f2bf(b.x); d[5]=f2bf(b.y); d[6]=f2bf(b.z); d[7]=f2bf(b.w);
}

// stage one 32KB chunk: wave w covers [w*2048, w*2048+2048) ushorts, 4 loads
#define STAGE(seq, bufi) do{ \
  const unsigned short* g_ = wsW + (size_t)(seq)*16384 + w*2048 + lane*8; \
  unsigned short* l_ = sh_stage + (bufi)*16384 + w*2048; \
  __builtin_amdgcn_global_load_lds((const __attribute__((address_space(1))) void*)(g_       ), (__attribute__((address_space(3))) void*)(l_       ), 16,0,0); \
  __builtin_amdgcn_global_load_lds((const __attribute__((address_space(1))) void*)(g_ +  512), (__attribute__((address_space(3))) void*)(l_ +  512), 16,0,0); \
  __builtin_amdgcn_global_load_lds((const __attribute__((address_space(1))) void*)(g_ + 1024), (__attribute__((address_space(3))) void*)(l_ + 1024), 16,0,0); \
  __builtin_amdgcn_global_load_lds((const __attribute__((address_space(1))) void*)(g_ + 1536), (__attribute__((address_space(3))) void*)(l_ + 1536), 16,0,0); \
}while(0)

// one chunk: wait seq-c loads, barrier, prefetch seq c+2 (wrap 48), 4 MFMAs
#define CHUNK(cl, MI, HS) do{ \
  const int c_  = (MI)*16 + (cl); \
  const int s2_ = (c_+2) % 48; \
  asm volatile("s_waitcnt vmcnt(4)" ::: "memory"); \
  __builtin_amdgcn_s_barrier(); \
  __builtin_amdgcn_sched_barrier(0); \
  STAGE(s2_, (c_+2)%3); \
  const unsigned short* sb_ = sh_stage + (c_%3)*16384 + lane*8; \
  const int gI_ = (cl)>>2, kh_ = (cl)&3; \
  s8v aA_ = read_afrag(HS, col, hi, 2*kh_+0); \
  s8v aB_ = read_afrag(HS, col, hi, 2*kh_+1); \
  { s8v wf_ = *(const s8v*)(sb_ + (0*16 + (w*2+0))*512); \
    acc[0][gI_] = MFMA16(aA_, wf_, acc[0][gI_]); } \
  { s8v wf_ = *(const s8v*)(sb_ + (0*16 + (w*2+1))*512); \
    acc[1][gI_] = MFMA16(aA_, wf_, acc[1][gI_]); } \
  { s8v wf_ = *(const s8v*)(sb_ + (1*16 + (w*2+0))*512); \
    acc[0][gI_] = MFMA16(aB_, wf_, acc[0][gI_]); } \
  { s8v wf_ = *(const s8v*)(sb_ + (1*16 + (w*2+1))*512); \
    acc[1][gI_] = MFMA16(aB_, wf_, acc[1][gI_]); } \
}while(0)

__global__ __launch_bounds__(TPB, 1)
void traj_mfma(const float* __restrict__ enc,   // B x 128
               const float* __restrict__ pos0,  // B x 2
               const float* __restrict__ ctx,   // B x 128
               const float* __restrict__ Wh,    // 512 x 128
               const float* __restrict__ bh,
               const float* __restrict__ Wc,
               const float* __restrict__ bc,
               const float* __restrict__ Wih0,  // 1024 x 130
               const float* __restrict__ bih0,
               const float* __restrict__ bhh0,
               const float* __restrict__ bih1,
               const float* __restrict__ bhh1,
               const float* __restrict__ Wp2,   // 2 x 64
               const float* __restrict__ bp1,
               const float* __restrict__ bp2,
               const unsigned short* __restrict__ wsW,
               unsigned* __restrict__ bar,      // [0]=count, [1]=generation
               float* __restrict__ out)         // B x 45 x 2
{
  __shared__ unsigned short sh_stage[3*16384]; // 96KB rotation (init: sh_x overlay)
  __shared__ unsigned short sh_gx[BB*1024];    // 32KB: ct fp32 (init) then gctx bf16
  __shared__ unsigned short sh_h0u[BB*HN];     // 8KB bf16 swizzled
  __shared__ unsigned short sh_h1u[BB*HN];     // 8KB
  __shared__ float sh_pos[BB][2];
  __shared__ float sh_red[4][BB][2];

  const int tid  = threadIdx.x;
  const int gb0  = blockIdx.x * BB;
  const int lane = tid & 63;
  const int w    = tid >> 6;        // 8 waves
  const int col  = lane & 15;
  const int hi   = lane >> 4;

  float* sh_xf = (float*)sh_stage;  // 8KB input staging overlay (init only)

  // ---- stage encoder_feat + pos ----
  {
    const float4* src = (const float4*)(enc + (size_t)gb0*DM);
    ((float4*)sh_xf)[tid] = src[tid];
  }
  if (tid < BB*2) ((float*)sh_pos)[tid] = pos0[(size_t)gb0*2 + tid];
  __syncthreads();

  // ---- h/c init: thread r computes h_all/c_all row r (fp32) ----
  {
    float* ctF = (float*)sh_gx;   // ct0 [16][256] | ct1 [16][256] (32KB)
    const int r = tid;
    float ah[BB], ac[BB];
    #pragma unroll
    for (int b=0;b<BB;b++){ ah[b]=0.f; ac[b]=0.f; }
    const float4* whr = (const float4*)(Wh + (size_t)r*DM);
    const float4* wcr = (const float4*)(Wc + (size_t)r*DM);
    #pragma nounroll
    for (int kk=0; kk<DM/4; kk++){
      float4 w0 = whr[kk], w1 = wcr[kk];
      #pragma unroll
      for (int b=0;b<BB;b++){
        float4 x = *(const float4*)&sh_xf[b*DM + kk*4];
        ah[b] += w0.x*x.x + w0.y*x.y + w0.z*x.z + w0.w*x.w;
        ac[b] += w1.x*x.x + w1.y*x.y + w1.z*x.z + w1.w*x.w;
      }
    }
    float bhv = bh[r], bcv = bc[r];
    if (r < HN){
      #pragma unroll
      for (int b=0;b<BB;b++){
        write_h(sh_h0u, b, r, ah[b] + bhv);
        ctF[(size_t)b*HN + r] = ac[b] + bcv;
      }
    } else {
      #pragma unroll
      for (int b=0;b<BB;b++){
        write_h(sh_h1u, b, r-HN, ah[b] + bhv);
        ctF[4096 + (size_t)b*HN + (r-HN)] = ac[b] + bcv;
      }
    }
  }
  __syncthreads();

  // ---- hoist c-state to regs ----
  float c0r[2][4], c1r[2][4];
  {
    const float* ctF = (const float*)sh_gx;
    #pragma unroll
    for (int m=0;m<2;m++){
      int uu = (w*2+m)*16 + col;
      #pragma unroll
      for (int q=0;q<4;q++){
        int b = hi*4+q;
        c0r[m][q] = ctF[(size_t)b*HN + uu];
        c1r[m][q] = ctF[4096 + (size_t)b*HN + uu];
      }
    }
  }
  __syncthreads();   // ct region free

  // ---- stage context ----
  {
    const float4* src = (const float4*)(ctx + (size_t)gb0*DM);
    ((float4*)sh_xf)[tid] = src[tid];
  }
  __syncthreads();

  // ---- gates_ctx -> bf16 LDS [16][1024] (persistent in sh_gx) ----
  {
    float a0[BB], a1[BB];
    #pragma unroll
    for (int b=0;b<BB;b++){ a0[b]=0.f; a1[b]=0.f; }
    const float2* wr0 = (const float2*)(Wih0 + (size_t)tid*130 + 2);
    const float2* wr1 = (const float2*)(Wih0 + (size_t)(tid+512)*130 + 2);
    #pragma nounroll
    for (int kk=0; kk<DM/2; kk++){
      float2 w0 = wr0[kk], w1 = wr1[kk];
      #pragma unroll
      for (int b=0;b<BB;b++){
        float2 x = *(const float2*)&sh_xf[b*DM + kk*2];
        a0[b] += w0.x*x.x + w0.y*x.y;
        a1[b] += w1.x*x.x + w1.y*x.y;
      }
    }
    float cb0 = bih0[tid]     + bhh0[tid];
    float cb1 = bih0[tid+512] + bhh0[tid+512];
    #pragma unroll
    for (int b=0;b<BB;b++){
      sh_gx[(size_t)b*1024 + tid]       = f2bf(a0[b] + cb0);
      sh_gx[(size_t)b*1024 + tid + 512] = f2bf(a1[b] + cb1);
    }
  }

  // ---- per-lane constants ----
  float wpr[2][4][2]; float b1r[2][4];
  #pragma unroll
  for (int m=0;m<2;m++){
    int uu = (w*2+m)*16 + col;
    #pragma unroll
    for (int g=0;g<4;g++){
      int j = (g<<8) + uu;
      wpr[m][g][0] = Wih0[(size_t)j*130 + 0];
      wpr[m][g][1] = Wih0[(size_t)j*130 + 1];
      b1r[m][g]    = bih1[j] + bhh1[j];
    }
  }
  const float bp1p = bp1[(w&3)*16 + col];
  const float w20  = Wp2[(w&3)*16 + col];
  const float w21  = Wp2[64 + (w&3)*16 + col];
  const float bp20 = bp2[0], bp21 = bp2[1];
  const unsigned short* wTp = wsW + 786432 + lane*8;   // Wp1 tiles
  __syncthreads();   // gctx visible; sh_stage free for rotation

  // ---- prologue: stage chunks 0,1 ----
  STAGE(0, 0);
  STAGE(1, 1);

  // ================= 45-step rollout =================
  #pragma nounroll
  for (int t=0; t<NSTEP; t++){
    // ---- layer0 acc init: gctx + pos ----
    f32x4 acc[2][4];
    #pragma unroll
    for (int m=0;m<2;m++){
      const int uu = (w*2+m)*16 + col;
      #pragma unroll
      for (int q=0;q<4;q++){
        float2 pp = *(const float2*)&sh_pos[hi*4+q][0];
        #pragma unroll
        for (int g=0;g<4;g++)
          acc[m][g][q] = bf2f(sh_gx[(size_t)(hi*4+q)*1024 + (g<<8) + uu])
                       + pp.x*wpr[m][g][0] + pp.y*wpr[m][g][1];
      }
    }

    // ---- Whh0 chunks 0..15 (A = h0 old) ----
    #pragma unroll
    for (int cl=0; cl<16; cl++){ CHUNK(cl, 0, sh_h0u); }
    __syncthreads();   // all h0-old reads done

    // ---- cell0 ----
    #pragma unroll
    for (int m=0;m<2;m++){
      int uu = (w*2+m)*16 + col;
      #pragma unroll
      for (int q=0;q<4;q++){
        float iv = sigm(acc[m][0][q]), fv = sigm(acc[m][1][q]);
        float gv = tanhx(acc[m][2][q]), ov = sigm(acc[m][3][q]);
        float cv = fv*c0r[m][q] + iv*gv;
        c0r[m][q] = cv;
        write_h(sh_h0u, hi*4+q, uu, ov*tanhx(cv));
      }
    }
    __syncthreads();   // new h0 visible

    // ---- layer1 acc init ----
    #pragma unroll
    for (int m=0;m<2;m++)
      #pragma unroll
      for (int g=0;g<4;g++)
        #pragma unroll
        for (int q=0;q<4;q++)
          acc[m][g][q] = b1r[m][g];

    // ---- Wih1 chunks (A = h0 new), Whh1 chunks (A = h1 old) ----
    #pragma unroll
    for (int cl=0; cl<16; cl++){ CHUNK(cl, 1, sh_h0u); }
    #pragma unroll
    for (int cl=0; cl<16; cl++){ CHUNK(cl, 2, sh_h1u); }
    __syncthreads();   // all h1-old reads done

    // ---- cell1 ----
    #pragma unroll
    for (int m=0;m<2;m++){
      int uu = (w*2+m)*16 + col;
      #pragma unroll
      for (int q=0;q<4;q++){
        float iv = sigm(acc[m][0][q]), fv = sigm(acc[m][1][q]);
        float gv = tanhx(acc[m][2][q]), ov = sigm(acc[m][3][q]);
        float cv = fv*c1r[m][q] + iv*gv;
        c1r[m][q] = cv;
        write_h(sh_h1u, hi*4+q, uu, ov*tanhx(cv));
      }
    }
    __syncthreads();   // new h1 visible

    // ---- head (waves 0..3; p-unit = (w&3)*16+col), Wp1 direct from L2 ----
    if (w < 4){
      f32x4 hp = {bp1p, bp1p, bp1p, bp1p};
      #pragma unroll
      for (int kt=0;kt<8;kt++){
        s8v a1n = read_afrag(sh_h1u, col, hi, kt);
        s8v wfp = *(const s8v*)(wTp + (size_t)((w&3)*8+kt)*512);
        hp = MFMA16(a1n, wfp, hp);
      }
      #pragma unroll
      for (int q=0;q<4;q++){
        float r  = fmaxf(hp[q], 0.f);
        float s0 = r*w20, s1 = r*w21;
        #pragma unroll
        for (int off=1; off<16; off<<=1){
          s0 += __shfl_xor(s0, off, 64);
          s1 += __shfl_xor(s1, off, 64);
        }
        if (col == 0){ sh_red[w][hi*4+q][0] = s0; sh_red[w][hi*4+q][1] = s1; }
      }
    }
    __syncthreads();   // sh_red complete

    // ---- combine, update pos, write out ----
    if (tid < BB*2){
      int b = tid >> 1, d = tid & 1;
      float s = sh_red[0][b][d] + sh_red[1][b][d] + sh_red[2][b][d] + sh_red[3][b][d]
              + (d ? bp21 : bp20);
      float np = sh_pos[b][d] + s;
      sh_pos[b][d] = np;
      out[((size_t)(gb0+b)*NSTEP + t)*2 + d] = np;
    }
    __syncthreads();   // pos stable for next step

    // ---- performance-only global step barrier (bounded spin, monotonic gen)
    // Aligns all 256 WGs each step so the weight sweep stays L2-resident.
    // If co-residency/timing fails, spins time out and results are UNCHANGED.
    if (t < NSTEP-1){
      if (tid == 0){
        unsigned tgt = (unsigned)(t+1);
        unsigned arrived = atomicAdd(bar, 1u) + 1u;
        if (arrived == NWG*tgt){
          atomicAdd(bar+1, 1u);                 // release generation t+1
        } else {
          int spin = 0;
          while (atomicAdd(bar+1, 0u) < tgt && spin < 30000){
            __builtin_amdgcn_s_sleep(8);
            ++spin;
          }
        }
      }
      __syncthreads();
    }
  }
}

extern "C" void kernel_launch(void* const* d_in, const int* in_sizes, int n_in,
                              void* d_out, int out_size, void* d_ws, size_t ws_size,
                              hipStream_t stream) {
  const float* enc  = (const float*)d_in[0];
  const float* pos0 = (const float*)d_in[1];
  const float* ctx  = (const float*)d_in[2];
  const float* Wh   = (const float*)d_in[3];
  const float* bh   = (const float*)d_in[4];
  const float* Wc   = (const float*)d_in[5];
  const float* bc   = (const float*)d_in[6];
  const float* Wih0 = (const float*)d_in[7];
  const float* Whh0 = (const float*)d_in[8];
  const float* bih0 = (const float*)d_in[9];
  const float* bhh0 = (const float*)d_in[10];
  const float* Wih1 = (const float*)d_in[11];
  const float* Whh1 = (const float*)d_in[12];
  const float* bih1 = (const float*)d_in[13];
  const float* bhh1 = (const float*)d_in[14];
  const float* Wp1  = (const float*)d_in[15];
  const float* bp1  = (const float*)d_in[16];
  const float* Wp2  = (const float*)d_in[17];
  const float* bp2  = (const float*)d_in[18];
  float* out = (float*)d_out;
  unsigned short* wsW = (unsigned short*)d_ws;
  unsigned* bar = (unsigned*)((char*)d_ws + BAR_OFF);

  // zero barrier words every launch (poison-safe; async -> graph-capture-safe)
  hipMemsetAsync((void*)bar, 0, 16, stream);

  hipLaunchKernelGGL(repack, dim3(392), dim3(256), 0, stream,
                     Whh0, Wih1, Whh1, Wp1, wsW);

  const int B = 4096;
  hipLaunchKernelGGL(traj_mfma, dim3(B / BB), dim3(TPB), 0, stream,
                     enc, pos0, ctx, Wh, bh, Wc, bc, Wih0, bih0, bhh0,
                     bih1, bhh1, Wp2, bp1, bp2, wsW, bar, out);
}

// Round 14
// 3931.892 us; speedup vs baseline: 1.1931x; 1.1931x over previous
//
#include <hip/hip_runtime.h>

// TrajectoryDecoder: 2-layer LSTM (H=256), 45 steps, B=4096.
// R14: BB=32 (128 WGs x 512 thr) to halve weight demand to 8.7GB, with a
// 5-deep / 7-buffer 16KB-chunk global_load_lds pipeline (98 chunks/step:
// 96 weight + 2 Wp1). No vmcnt drain anywhere in the loop: phase barriers
// wait lgkmcnt only; Wp1 is part of the chunk rotation. vmcnt(8) per chunk
// (5 chunks x 2 loads in flight). gctx packed-bf16 in regs; 256-VGPR budget.
// All loop indices compile-time (rule #20).
// mfma_f32_16x16x32_bf16: A row=lane&15(batch), k=(lane>>4)*8+j;
//   B col=lane&15(gate unit); C/D row=(lane>>4)*4+q, col=lane&15.

#define BB    32
#define TPB   512
#define HN    256
#define DM    128
#define NSTEP 45
#define NCH   98
#define NBUF  7
#define DEPTH 5

typedef __attribute__((ext_vector_type(8))) short s8v;
typedef __attribute__((ext_vector_type(4))) float f32x4;

#define MFMA16(a,b,c) __builtin_amdgcn_mfma_f32_16x16x32_bf16((a),(b),(c),0,0,0)

__device__ __forceinline__ unsigned short f2bf(float f){
  union { float f; unsigned u; } x; x.f = f;
  unsigned r = x.u + 0x7fffu + ((x.u >> 16) & 1u);
  return (unsigned short)(r >> 16);
}
__device__ __forceinline__ float bf2f(unsigned short h){
  union { unsigned u; float f; } x; x.u = ((unsigned)h) << 16;
  return x.f;
}
__device__ __forceinline__ float sigm(float x){
  x = fminf(40.f, fmaxf(-40.f, x));
  return 1.f/(1.f + __expf(-x));
}
__device__ __forceinline__ float tanhx(float x){
  float xx = fminf(15.f, fmaxf(-15.f, x));
  float e = __expf(2.f*xx);
  return (e-1.f)/(e+1.f);
}

// h LDS: bf16 [32 rows][256], row b element u stored at u ^ ((b&7)<<3)
__device__ __forceinline__ void write_h(unsigned short* lds, int b, int u, float v){
  lds[b*HN + (u ^ ((b&7)<<3))] = f2bf(v);
}
__device__ __forceinline__ s8v read_afrag(const unsigned short* lds, int b, int hi, int kt){
  int blk = (kt*4 + hi) ^ (b & 7);
  return *(const s8v*)(lds + b*HN + blk*8);
}

// ---- repack (R10 layout, unchanged): chunk c base = c*8192 ushorts ----
// d_ws (ushort): Whh0[262144] | Wih1[262144] | Whh1[262144] | Wp1[16384]
// big: tile r=(g*8+kt)*16+ut at mi*262144+r*512+lane*8 holds
//   W[g*256+ut*16+(lane&15)][kt*32+(lane>>4)*8+j]
// Wp1: tile r2=pt*8+kt at 786432+r2*512+lane*8, row pt*16+(lane&15).
__global__ void repack(const float* __restrict__ Whh0, const float* __restrict__ Wih1,
                       const float* __restrict__ Whh1, const float* __restrict__ Wp1,
                       unsigned short* __restrict__ dst){
  int gid  = blockIdx.x*256 + threadIdx.x;
  int lane = gid & 63;
  int tile = gid >> 6;
  const float* src; int row; size_t doff;
  int k0 = (lane>>4)*8;
  if (tile < 1536){
    int mi = tile / 512;
    int r  = tile % 512;          // (g*8+kt)*16+ut
    int ut = r & 15;
    int kt = (r >> 4) & 7;
    int g  = r >> 7;
    src  = (mi==0) ? Whh0 : (mi==1) ? Wih1 : Whh1;
    row  = g*256 + ut*16 + (lane&15);
    k0  += kt*32;
    doff = (size_t)mi*262144 + (size_t)r*512 + lane*8;
  } else {
    int r2 = tile - 1536;         // pt*8+kt
    int kt = r2 & 7, pt = r2 >> 3;
    src  = Wp1;
    row  = pt*16 + (lane&15);
    k0  += kt*32;
    doff = 786432 + (size_t)r2*512 + lane*8;
  }
  const float* s = src + (size_t)row*HN + k0;
  float4 a = *(const float4*)(s);
  float4 b = *(const float4*)(s+4);
  unsigned short* d = dst + doff;
  d[0]=f2bf(a.x); d[1]=f2bf(a.y); d[2]=f2bf(a.z); d[3]=f2bf(a.w);
  d[4]=f2bf(b.x); d[5]=f2bf(b.y); d[6]=f2bf(b.z); d[7]=f2bf(b.w);
}

// stage one 16KB chunk: wave w covers [w*1024, w*1024+1024) ushorts, 2 loads
#define STAGE16(seq) do{ \
  const unsigned short* g_ = wsW + (size_t)(seq)*8192 + w*1024 + lane*8; \
  unsigned short* l_ = sh_stage + (size_t)((seq)%NBUF)*8192 + w*1024; \
  __builtin_amdgcn_global_load_lds((const __attribute__((address_space(1))) void*)(g_      ), (__attribute__((address_space(3))) void*)(l_      ), 16,0,0); \
  __builtin_amdgcn_global_load_lds((const __attribute__((address_space(1))) void*)(g_ + 512), (__attribute__((address_space(3))) void*)(l_ + 512), 16,0,0); \
}while(0)

// one chunk: wait own seq loads (5 deep x2 = 10 out; retire oldest 2),
// barrier (all waves' slices landed), prefetch seq+5, 4 MFMAs (2m x 2bq).
#define CHUNK16(cl, MI, HS) do{ \
  const int c_ = (MI)*32 + (cl); \
  asm volatile("s_waitcnt vmcnt(8)" ::: "memory"); \
  __builtin_amdgcn_s_barrier(); \
  __builtin_amdgcn_sched_barrier(0); \
  STAGE16((c_+DEPTH)%NCH); \
  const unsigned short* sb_ = sh_stage + (size_t)((c_)%NBUF)*8192 + lane*8; \
  const int g_ = (cl)>>3, kt_ = (cl)&7; \
  s8v aA0_ = read_afrag(HS, col,    hi, kt_); \
  s8v aA1_ = read_afrag(HS, 16+col, hi, kt_); \
  s8v wf0_ = *(const s8v*)(sb_ + (w*2+0)*512); \
  s8v wf1_ = *(const s8v*)(sb_ + (w*2+1)*512); \
  acc[0][g_][0] = MFMA16(aA0_, wf0_, acc[0][g_][0]); \
  acc[0][g_][1] = MFMA16(aA1_, wf0_, acc[0][g_][1]); \
  acc[1][g_][0] = MFMA16(aA0_, wf1_, acc[1][g_][0]); \
  acc[1][g_][1] = MFMA16(aA1_, wf1_, acc[1][g_][1]); \
}while(0)

// head-chunk: wait + barrier + prefetch only (data consumed after)
#define HSTAGE(cLit) do{ \
  asm volatile("s_waitcnt vmcnt(8)" ::: "memory"); \
  __builtin_amdgcn_s_barrier(); \
  __builtin_amdgcn_sched_barrier(0); \
  STAGE16(((cLit)+DEPTH)%NCH); \
}while(0)

// phase barrier: publish LDS writes without draining vmcnt (keeps pipeline)
#define PHASE_BAR() do{ \
  asm volatile("s_waitcnt lgkmcnt(0)" ::: "memory"); \
  __builtin_amdgcn_s_barrier(); \
  __builtin_amdgcn_sched_barrier(0); \
}while(0)

__global__ __launch_bounds__(TPB, 1)
void traj_mfma(const float* __restrict__ enc,   // B x 128
               const float* __restrict__ pos0,  // B x 2
               const float* __restrict__ ctx,   // B x 128
               const float* __restrict__ Wh,    // 512 x 128
               const float* __restrict__ bh,
               const float* __restrict__ Wc,
               const float* __restrict__ bc,
               const float* __restrict__ Wih0,  // 1024 x 130
               const float* __restrict__ bih0,
               const float* __restrict__ bhh0,
               const float* __restrict__ bih1,
               const float* __restrict__ bhh1,
               const float* __restrict__ Wp2,   // 2 x 64
               const float* __restrict__ bp1,
               const float* __restrict__ bp2,
               const unsigned short* __restrict__ wsW,
               float* __restrict__ out)         // B x 45 x 2
{
  __shared__ unsigned short sh_stage[NBUF*8192]; // 112KB rotation (init overlays)
  __shared__ unsigned short sh_h0u[BB*HN];       // 16KB bf16 swizzled
  __shared__ unsigned short sh_h1u[BB*HN];       // 16KB
  __shared__ float sh_pos[BB][2];                // 256B
  __shared__ float sh_red[4][BB][2];             // 1KB

  const int tid  = threadIdx.x;
  const int gb0  = blockIdx.x * BB;
  const int lane = tid & 63;
  const int w    = tid >> 6;        // 8 waves
  const int col  = lane & 15;
  const int hi   = lane >> 4;

  float* sh_xf = (float*)sh_stage;  // 16KB input overlay (init only)

  // ---- stage encoder_feat + pos ----
  {
    const float4* src = (const float4*)(enc + (size_t)gb0*DM);
    float4* dst = (float4*)sh_xf;
    dst[tid] = src[tid];
    dst[tid+512] = src[tid+512];
  }
  if (tid < BB*2) ((float*)sh_pos)[tid] = pos0[(size_t)gb0*2 + tid];
  __syncthreads();

  // ---- h/c init: thread r computes h/c row r, 2 passes of 16 batches ----
  {
    float* ctF = (float*)(sh_stage + 8192);  // ct0[32][256]|ct1[32][256] 64KB
    const int r = tid;
    const float4* whr = (const float4*)(Wh + (size_t)r*DM);
    const float4* wcr = (const float4*)(Wc + (size_t)r*DM);
    float bhv = bh[r], bcv = bc[r];
    #pragma nounroll
    for (int half=0; half<2; half++){
      float ah[16], ac2[16];
      #pragma unroll
      for (int b=0;b<16;b++){ ah[b]=0.f; ac2[b]=0.f; }
      #pragma nounroll
      for (int kk=0; kk<DM/4; kk++){
        float4 w0 = whr[kk], w1 = wcr[kk];
        #pragma unroll
        for (int b=0;b<16;b++){
          float4 x = *(const float4*)&sh_xf[(half*16+b)*DM + kk*4];
          ah[b]  += w0.x*x.x + w0.y*x.y + w0.z*x.z + w0.w*x.w;
          ac2[b] += w1.x*x.x + w1.y*x.y + w1.z*x.z + w1.w*x.w;
        }
      }
      if (r < HN){
        #pragma unroll
        for (int b=0;b<16;b++){
          write_h(sh_h0u, half*16+b, r, ah[b] + bhv);
          ctF[(size_t)(half*16+b)*HN + r] = ac2[b] + bcv;
        }
      } else {
        #pragma unroll
        for (int b=0;b<16;b++){
          write_h(sh_h1u, half*16+b, r-HN, ah[b] + bhv);
          ctF[8192 + (size_t)(half*16+b)*HN + (r-HN)] = ac2[b] + bcv;
        }
      }
    }
  }
  __syncthreads();

  // ---- hoist c-state to regs ----
  float c0r[2][2][4], c1r[2][2][4];   // [m][bq][q]
  {
    const float* ctF = (const float*)(sh_stage + 8192);
    #pragma unroll
    for (int m=0;m<2;m++){
      int uu = (w*2+m)*16 + col;
      #pragma unroll
      for (int bq=0;bq<2;bq++)
        #pragma unroll
        for (int q=0;q<4;q++){
          int b = bq*16 + hi*4 + q;
          c0r[m][bq][q] = ctF[(size_t)b*HN + uu];
          c1r[m][bq][q] = ctF[8192 + (size_t)b*HN + uu];
        }
    }
  }
  __syncthreads();   // ct region free

  // ---- stage context ----
  {
    const float4* src = (const float4*)(ctx + (size_t)gb0*DM);
    float4* dst = (float4*)sh_xf;
    dst[tid] = src[tid];
    dst[tid+512] = src[tid+512];
  }
  __syncthreads();

  // ---- gates_ctx -> bf16 scratch [32][1024] @+8192; rows tid, tid+512 ----
  {
    unsigned short* gxu = sh_stage + 8192;
    const float2* wr0 = (const float2*)(Wih0 + (size_t)tid*130 + 2);
    const float2* wr1 = (const float2*)(Wih0 + (size_t)(tid+512)*130 + 2);
    float cb0 = bih0[tid]     + bhh0[tid];
    float cb1 = bih0[tid+512] + bhh0[tid+512];
    #pragma nounroll
    for (int half=0; half<2; half++){
      float a0[16], a1[16];
      #pragma unroll
      for (int b=0;b<16;b++){ a0[b]=0.f; a1[b]=0.f; }
      #pragma nounroll
      for (int kk=0; kk<DM/2; kk++){
        float2 w0 = wr0[kk], w1 = wr1[kk];
        #pragma unroll
        for (int b=0;b<16;b++){
          float2 x = *(const float2*)&sh_xf[(half*16+b)*DM + kk*2];
          a0[b] += w0.x*x.x + w0.y*x.y;
          a1[b] += w1.x*x.x + w1.y*x.y;
        }
      }
      #pragma unroll
      for (int b=0;b<16;b++){
        gxu[(size_t)(half*16+b)*1024 + tid]       = f2bf(a0[b] + cb0);
        gxu[(size_t)(half*16+b)*1024 + tid + 512] = f2bf(a1[b] + cb1);
      }
    }
  }
  __syncthreads();

  // ---- hoist gctx to PACKED bf16 regs: gregp[m][g][bq][j] ----
  unsigned gregp[2][4][2][2];
  {
    const unsigned short* gxu = sh_stage + 8192;
    #pragma unroll
    for (int m=0;m<2;m++){
      int uu = (w*2+m)*16 + col;
      #pragma unroll
      for (int g=0;g<4;g++)
        #pragma unroll
        for (int bq=0;bq<2;bq++)
          #pragma unroll
          for (int j=0;j<2;j++){
            unsigned lo = gxu[(size_t)(bq*16+hi*4+2*j  )*1024 + (g<<8) + uu];
            unsigned hv = gxu[(size_t)(bq*16+hi*4+2*j+1)*1024 + (g<<8) + uu];
            gregp[m][g][bq][j] = lo | (hv << 16);
          }
    }
  }

  // ---- per-lane constants ----
  float wpr[2][4][2]; float b1r[2][4];
  #pragma unroll
  for (int m=0;m<2;m++){
    int uu = (w*2+m)*16 + col;
    #pragma unroll
    for (int g=0;g<4;g++){
      int j = (g<<8) + uu;
      wpr[m][g][0] = Wih0[(size_t)j*130 + 0];
      wpr[m][g][1] = Wih0[(size_t)j*130 + 1];
      b1r[m][g]    = bih1[j] + bhh1[j];
    }
  }
  const int   pt   = w & 3;
  const int   bqh  = w >> 2;
  const float bp1p = bp1[pt*16 + col];
  const float w20  = Wp2[pt*16 + col];
  const float w21  = Wp2[64 + pt*16 + col];
  const float bp20 = bp2[0], bp21 = bp2[1];
  __syncthreads();   // overlays free -> staging rotation

  // ---- prologue: stage chunks 0..4 ----
  STAGE16(0); STAGE16(1); STAGE16(2); STAGE16(3); STAGE16(4);

  // ================= 45-step rollout =================
  #pragma nounroll
  for (int t=0; t<NSTEP; t++){
    // ---- layer0 acc init: gctx(packed) + pos ----
    f32x4 acc[2][4][2];   // [m][g][bq]
    {
      float p0q[2][4], p1q[2][4];
      #pragma unroll
      for (int bq=0;bq<2;bq++)
        #pragma unroll
        for (int q=0;q<4;q++){
          float2 pp = *(const float2*)&sh_pos[bq*16+hi*4+q][0];
          p0q[bq][q]=pp.x; p1q[bq][q]=pp.y;
        }
      #pragma unroll
      for (int m=0;m<2;m++)
        #pragma unroll
        for (int g=0;g<4;g++)
          #pragma unroll
          for (int bq=0;bq<2;bq++)
            #pragma unroll
            for (int j=0;j<2;j++){
              unsigned u = gregp[m][g][bq][j];
              acc[m][g][bq][2*j]   = bf2f((unsigned short)(u & 0xffffu))
                                   + p0q[bq][2*j]  *wpr[m][g][0] + p1q[bq][2*j]  *wpr[m][g][1];
              acc[m][g][bq][2*j+1] = bf2f((unsigned short)(u >> 16))
                                   + p0q[bq][2*j+1]*wpr[m][g][0] + p1q[bq][2*j+1]*wpr[m][g][1];
            }
    }

    // ---- Whh0 chunks 0..31 (A = h0 old) ----
    #pragma unroll
    for (int cl=0; cl<32; cl++){ CHUNK16(cl, 0, sh_h0u); }
    PHASE_BAR();   // all h0-old reads complete

    // ---- cell0 ----
    #pragma unroll
    for (int m=0;m<2;m++){
      int uu = (w*2+m)*16 + col;
      #pragma unroll
      for (int bq=0;bq<2;bq++)
        #pragma unroll
        for (int q=0;q<4;q++){
          float iv = sigm(acc[m][0][bq][q]), fv = sigm(acc[m][1][bq][q]);
          float gv = tanhx(acc[m][2][bq][q]), ov = sigm(acc[m][3][bq][q]);
          float cv = fv*c0r[m][bq][q] + iv*gv;
          c0r[m][bq][q] = cv;
          write_h(sh_h0u, bq*16+hi*4+q, uu, ov*tanhx(cv));
        }
    }
    PHASE_BAR();   // h0 new published

    // ---- layer1 acc init ----
    #pragma unroll
    for (int m=0;m<2;m++)
      #pragma unroll
      for (int g=0;g<4;g++)
        #pragma unroll
        for (int bq=0;bq<2;bq++)
          #pragma unroll
          for (int q=0;q<4;q++)
            acc[m][g][bq][q] = b1r[m][g];

    // ---- Wih1 chunks 32..63 (A = h0 new), Whh1 chunks 64..95 (A = h1 old) ----
    #pragma unroll
    for (int cl=0; cl<32; cl++){ CHUNK16(cl, 1, sh_h0u); }
    #pragma unroll
    for (int cl=0; cl<32; cl++){ CHUNK16(cl, 2, sh_h1u); }
    PHASE_BAR();   // all h1-old reads complete

    // ---- cell1 ----
    #pragma unroll
    for (int m=0;m<2;m++){
      int uu = (w*2+m)*16 + col;
      #pragma unroll
      for (int bq=0;bq<2;bq++)
        #pragma unroll
        for (int q=0;q<4;q++){
          float iv = sigm(acc[m][0][bq][q]), fv = sigm(acc[m][1][bq][q]);
          float gv = tanhx(acc[m][2][bq][q]), ov = sigm(acc[m][3][bq][q]);
          float cv = fv*c1r[m][bq][q] + iv*gv;
          c1r[m][bq][q] = cv;
          write_h(sh_h1u, bq*16+hi*4+q, uu, ov*tanhx(cv));
        }
    }
    PHASE_BAR();   // h1 new published

    // ---- Wp1 chunks 96,97 land; head from stage LDS (no flat loads) ----
    HSTAGE(96);
    HSTAGE(97);
    {
      // pt 0,1 in chunk 96 (buf 96%7=5); pt 2,3 in chunk 97 (buf 6)
      const unsigned short* hb = sh_stage
          + (size_t)((96 + (pt>>1)) % NBUF)*8192 + (pt&1)*8*512 + lane*8;
      f32x4 hp = {bp1p, bp1p, bp1p, bp1p};
      #pragma unroll
      for (int kt=0;kt<8;kt++){
        s8v a1n = read_afrag(sh_h1u, bqh*16+col, hi, kt);
        s8v wfp = *(const s8v*)(hb + kt*512);
        hp = MFMA16(a1n, wfp, hp);
      }
      #pragma unroll
      for (int q=0;q<4;q++){
        float r  = fmaxf(hp[q], 0.f);
        float s0 = r*w20, s1 = r*w21;
        #pragma unroll
        for (int off=1; off<16; off<<=1){
          s0 += __shfl_xor(s0, off, 64);
          s1 += __shfl_xor(s1, off, 64);
        }
        if (col == 0){
          sh_red[pt][bqh*16+hi*4+q][0] = s0;
          sh_red[pt][bqh*16+hi*4+q][1] = s1;
        }
      }
    }
    PHASE_BAR();   // sh_red complete

    // ---- combine, update pos, write out ----
    if (tid < BB*2){
      int b = tid >> 1, d = tid & 1;
      float s = sh_red[0][b][d] + sh_red[1][b][d] + sh_red[2][b][d] + sh_red[3][b][d]
              + (d ? bp21 : bp20);
      float np = sh_pos[b][d] + s;
      sh_pos[b][d] = np;
      out[((size_t)(gb0+b)*NSTEP + t)*2 + d] = np;
    }
    PHASE_BAR();   // pos stable for next step
  }
}

extern "C" void kernel_launch(void* const* d_in, const int* in_sizes, int n_in,
                              void* d_out, int out_size, void* d_ws, size_t ws_size,
                              hipStream_t stream) {
  const float* enc  = (const float*)d_in[0];
  const float* pos0 = (const float*)d_in[1];
  const float* ctx  = (const float*)d_in[2];
  const float* Wh   = (const float*)d_in[3];
  const float* bh   = (const float*)d_in[4];
  const float* Wc   = (const float*)d_in[5];
  const float* bc   = (const float*)d_in[6];
  const float* Wih0 = (const float*)d_in[7];
  const float* Whh0 = (const float*)d_in[8];
  const float* bih0 = (const float*)d_in[9];
  const float* bhh0 = (const float*)d_in[10];
  const float* Wih1 = (const float*)d_in[11];
  const float* Whh1 = (const float*)d_in[12];
  const float* bih1 = (const float*)d_in[13];
  const float* bhh1 = (const float*)d_in[14];
  const float* Wp1  = (const float*)d_in[15];
  const float* bp1  = (const float*)d_in[16];
  const float* Wp2  = (const float*)d_in[17];
  const float* bp2  = (const float*)d_in[18];
  float* out = (float*)d_out;
  unsigned short* wsW = (unsigned short*)d_ws;

  hipLaunchKernelGGL(repack, dim3(392), dim3(256), 0, stream,
                     Whh0, Wih1, Whh1, Wp1, wsW);

  const int B = 4096;
  hipLaunchKernelGGL(traj_mfma, dim3(B / BB), dim3(TPB), 0, stream,
                     enc, pos0, ctx, Wh, bh, Wc, bc, Wih0, bih0, bhh0,
                     bih1, bhh1, Wp2, bp1, bp2, wsW, out);
}